// Round 9
// baseline (351.049 us; speedup 1.0000x reference)
//
#include <hip/hip_runtime.h>
#include <math.h>

#define T_SEQ 2048
#define C_DIM 2048
#define NH    16
#define NG    4
#define DH    128
#define BATCH 2

typedef unsigned short u16;
typedef unsigned long long u64;
typedef __bf16 bf16_t;
typedef bf16_t bf16x8 __attribute__((ext_vector_type(8)));
typedef float  f32x4  __attribute__((ext_vector_type(4)));

static __device__ __forceinline__ u16 f2bf(float f) {
    return __builtin_bit_cast(u16, (__bf16)f);
}

// async global->LDS, 16B per lane. lds must be wave-uniform base; HW adds lane*16.
static __device__ __forceinline__ void gll16(const void* g, void* lds) {
    __builtin_amdgcn_global_load_lds(
        (const __attribute__((address_space(1))) void*)(unsigned long long)(g),
        (__attribute__((address_space(3))) void*)(unsigned int)(unsigned long long)(lds),
        16, 0, 0);
}

// ---------------------------------------------------------------------------
// prep = fused fp32->bf16 cast (x, Wq, Wk, Wv, Wo) + rope tables.
// blocks [0,9216): cast, 8 elems/thread; [9216, 9728): cos/sin tables.
// chunks: x 1048576 | Wq 524288 | Wk 131072 | Wv 131072 | Wo 524288
// ---------------------------------------------------------------------------
__global__ __launch_bounds__(256)
void prep(const float* __restrict__ x,  const float* __restrict__ wq,
          const float* __restrict__ wk, const float* __restrict__ wv,
          const float* __restrict__ wo,
          u16* __restrict__ xo, u16* __restrict__ wqo,
          u16* __restrict__ wko, u16* __restrict__ wvo,
          u16* __restrict__ woo,
          float* __restrict__ cosT, float* __restrict__ sinT) {
    const int bid = blockIdx.x;
    if (bid < 9216) {
        int i = bid * 256 + threadIdx.x;
        const float* src; u16* dst; int off;
        if (i < 1048576)      { src = x;  dst = xo;  off = i; }
        else if (i < 1572864) { src = wq; dst = wqo; off = i - 1048576; }
        else if (i < 1703936) { src = wk; dst = wko; off = i - 1572864; }
        else if (i < 1835008) { src = wv; dst = wvo; off = i - 1703936; }
        else                  { src = wo; dst = woo; off = i - 1835008; }
        const float4* p = (const float4*)src + (size_t)off * 2;
        float4 a = p[0], b = p[1];
        u16 u[8] = {f2bf(a.x), f2bf(a.y), f2bf(a.z), f2bf(a.w),
                    f2bf(b.x), f2bf(b.y), f2bf(b.z), f2bf(b.w)};
        *(uint4*)(dst + (size_t)off * 8) = *(const uint4*)u;
    } else {
        int i = (bid - 9216) * 256 + threadIdx.x;   // 131072 entries
        int tp = i >> 6, ln = i & 63;
        float invfreq = __builtin_amdgcn_exp2f(-(float)ln * (13.287712379549449f / 64.0f));
        float s, c;
        sincosf((float)tp * invfreq, &s, &c);
        cosT[i] = c;
        sinT[i] = s;
    }
}

// ---------------------------------------------------------------------------
// GEMM core: acc(64x64 per wave) = A_bf16(M,K) @ B_bf16(N,K)^T for one
// 128x128 tile, BK=32, 4 waves. Epilogue supplied by caller.
// ---------------------------------------------------------------------------
static __device__ __forceinline__ void gemm_core(
        u16* As, u16* Bs,
        const u16* __restrict__ A, const u16* __restrict__ B,
        int K, int m0, int n0, f32x4 (&acc)[4][4]) {
    const int t    = threadIdx.x;
    const int lane = t & 63, w = t >> 6;
    const int l15  = lane & 15, quad = lane >> 4;
    const int wr   = w >> 1, wc = w & 1;

#pragma unroll
    for (int mt = 0; mt < 4; ++mt)
#pragma unroll
        for (int nt = 0; nt < 4; ++nt) acc[mt][nt] = (f32x4){0.f, 0.f, 0.f, 0.f};

    const int off0 = w*2048 + lane*16;
    const int r0 = off0 >> 6,          c0 = (off0 & 63) >> 1;
    const int r1 = (off0+1024) >> 6,   c1 = ((off0+1024) & 63) >> 1;
    const u16* Ag0 = A + (size_t)(m0 + r0) * K + c0;
    const u16* Ag1 = A + (size_t)(m0 + r1) * K + c1;
    const u16* Bg0 = B + (size_t)(n0 + r0) * K + c0;
    const u16* Bg1 = B + (size_t)(n0 + r1) * K + c1;
    char* AsB = (char*)As; char* BsB = (char*)Bs;
    const int ldsOff0 = w*2048, ldsOff1 = w*2048 + 1024;

    for (int k0 = 0; k0 < K; k0 += 32) {
        gll16(Ag0 + k0, AsB + ldsOff0);
        gll16(Ag1 + k0, AsB + ldsOff1);
        gll16(Bg0 + k0, BsB + ldsOff0);
        gll16(Bg1 + k0, BsB + ldsOff1);
        __syncthreads();
        bf16x8 af[4], bf[4];
#pragma unroll
        for (int mt = 0; mt < 4; ++mt)
            af[mt] = __builtin_bit_cast(bf16x8,
                *(const uint4*)&As[(wr*64 + mt*16 + l15)*32 + quad*8]);
#pragma unroll
        for (int nt = 0; nt < 4; ++nt)
            bf[nt] = __builtin_bit_cast(bf16x8,
                *(const uint4*)&Bs[(wc*64 + nt*16 + l15)*32 + quad*8]);
#pragma unroll
        for (int mt = 0; mt < 4; ++mt)
#pragma unroll
            for (int nt = 0; nt < 4; ++nt)
                acc[mt][nt] = __builtin_amdgcn_mfma_f32_16x16x32_bf16(
                                  af[mt], bf[nt], acc[mt][nt], 0, 0, 0);
        __syncthreads();
    }
}

__global__ __launch_bounds__(256)
void gemm_nt_bf16(const u16* __restrict__ A, const u16* __restrict__ B,
                  const float* __restrict__ bias, float* __restrict__ C,
                  int N, int K) {
    __shared__ __align__(16) u16 As[128*32];
    __shared__ __align__(16) u16 Bs[128*32];
    const int m0 = blockIdx.y*128, n0 = blockIdx.x*128;
    f32x4 acc[4][4];
    gemm_core(As, Bs, A, B, K, m0, n0, acc);

    const int t    = threadIdx.x;
    const int lane = t & 63, w = t >> 6;
    const int l15  = lane & 15, quad = lane >> 4;
    const int wr   = w >> 1, wc = w & 1;
#pragma unroll
    for (int mt = 0; mt < 4; ++mt)
#pragma unroll
        for (int nt = 0; nt < 4; ++nt) {
            const int col = n0 + wc*64 + nt*16 + l15;
            const float bv = bias ? bias[col] : 0.f;
#pragma unroll
            for (int r = 0; r < 4; ++r) {
                const int row = m0 + wr*64 + mt*16 + quad*4 + r;
                C[(size_t)row * N + col] = acc[mt][nt][r] + bv;
            }
        }
}

// ---------------------------------------------------------------------------
// Fused Q/K/V projections (v13). blockIdx.x 0..15 -> Q, 16..19 -> K, 20..23 -> V.
// Q/K: plain fp32 store (round-6 verified; rmsnorm kernel consumes).
// V:   bf16 store in NATURAL (B,T,G,D) order (v11-verified path; coalesced
//      32B runs, register-neutral). v12 lesson: transposed epilogue stores
//      scatter 8B segments across T-rows -> +35us; transpose stays in its
//      own LDS-tiled kernel.
// ---------------------------------------------------------------------------
__global__ __launch_bounds__(256)
void gemm_qkv(const u16* __restrict__ A,  const u16* __restrict__ Bq,
              const u16* __restrict__ Bk, const u16* __restrict__ Bv,
              float* __restrict__ Cq, float* __restrict__ Ck,
              u16* __restrict__ vfh) {
    __shared__ __align__(16) u16 As[128*32];
    __shared__ __align__(16) u16 Bs[128*32];
    const int bx = blockIdx.x;
    const u16* B; int N, n0, mode;
    if (bx < 16)      { B = Bq; N = 2048; n0 = bx * 128;      mode = 0; }
    else if (bx < 20) { B = Bk; N = 512;  n0 = (bx-16) * 128; mode = 1; }
    else              { B = Bv; N = 512;  n0 = (bx-20) * 128; mode = 2; }
    const int m0 = blockIdx.y * 128;

    f32x4 acc[4][4];
    gemm_core(As, Bs, A, B, 2048, m0, n0, acc);

    const int t    = threadIdx.x;
    const int lane = t & 63, w = t >> 6;
    const int l15  = lane & 15, quad = lane >> 4;
    const int wr   = w >> 1, wc = w & 1;

    if (mode == 2) {                   // V: bf16, natural (B,T,G,D) order
#pragma unroll
        for (int mt = 0; mt < 4; ++mt)
#pragma unroll
            for (int nt = 0; nt < 4; ++nt) {
                const int col = n0 + wc*64 + nt*16 + l15;
#pragma unroll
                for (int r = 0; r < 4; ++r) {
                    const int row = m0 + wr*64 + mt*16 + quad*4 + r;
                    vfh[(size_t)row * 512 + col] = f2bf(acc[mt][nt][r]);
                }
            }
        return;
    }

    float* C = mode ? Ck : Cq;
#pragma unroll
    for (int mt = 0; mt < 4; ++mt)
#pragma unroll
        for (int nt = 0; nt < 4; ++nt) {
            const int col = n0 + wc*64 + nt*16 + l15;
#pragma unroll
            for (int r = 0; r < 4; ++r) {
                const int row = m0 + wr*64 + mt*16 + quad*4 + r;
                C[(size_t)row * N + col] = acc[mt][nt][r];
            }
        }
}

// ---------------------------------------------------------------------------
// norm_qk_vt = fused RMSNorm+RoPE (q,k: fp32 in -> bf16 out) + V transpose
// (bf16 (B,T,G,D) -> (B,G,D,T)).
// blocks [0,16384): q rows | [16384,20480): k rows | [20480,20736): V tiles.
// ---------------------------------------------------------------------------
__global__ __launch_bounds__(256)
void norm_qk_vt(const float* __restrict__ qf, const float* __restrict__ kf,
                const float* __restrict__ qw, const float* __restrict__ kw,
                const float* __restrict__ cosT, const float* __restrict__ sinT,
                const u16* __restrict__ vfh,
                u16* __restrict__ qo, u16* __restrict__ ko, u16* __restrict__ vt) {
    __shared__ u16 Lt[128 * 66];
    const int blk = blockIdx.x;
    const int t   = threadIdx.x;

    if (blk < 20480) {
        const int sub  = t >> 6;
        const int lane = t & 63;
        const float* in; const float* w; u16* out; int row, nheads; float scale;
        if (blk < 16384) {
            in = qf; w = qw; out = qo; nheads = NH; scale = 0.08838834764831845f;
            row = blk * 4 + sub;
        } else {
            in = kf; w = kw; out = ko; nheads = NG; scale = 1.0f;
            row = (blk - 16384) * 4 + sub;
        }
        const float* p = in + (size_t)row * 128;
        float x1 = p[lane], x2 = p[lane + 64];
        float ss = x1*x1 + x2*x2;
#pragma unroll
        for (int off = 32; off >= 1; off >>= 1) ss += __shfl_xor(ss, off, 64);
        float inv = 1.0f / (sqrtf(ss * (1.0f/128.0f)) + 1e-6f);
        float x1n = w[lane]      * x1 * inv;
        float x2n = w[lane + 64] * x2 * inv;
        int tpos = (row / nheads) & (T_SEQ - 1);
        float c = cosT[tpos*64 + lane];
        float s = sinT[tpos*64 + lane];
        out[(size_t)row*128 + lane]      = f2bf((x1n * c + x2n * s) * scale);
        out[(size_t)row*128 + lane + 64] = f2bf((x2n * c - x1n * s) * scale);
        return;
    }

    // V transpose: idx in [0,256): 32 t-tiles x 8 (b,g)
    const int idx = blk - 20480;
    const int t0  = (idx & 31) * 64;
    const int bg  = idx >> 5;
    const int b   = bg / NG, g = bg % NG;
#pragma unroll
    for (int rep = 0; rep < 4; ++rep) {
        int ii = rep * 256 + t;                // 0..1023
        int i  = ii >> 4;                      // row 0..63
        int c  = ii & 15;                      // 8-elem chunk
        uint4 vv = *(const uint4*)(vfh + ((size_t)(b*T_SEQ + t0 + i)*NG + g)*DH + c*8);
        const u16* pv = (const u16*)&vv;
#pragma unroll
        for (int jj = 0; jj < 8; ++jj)
            Lt[(c*8 + jj)*66 + i] = pv[jj];
    }
    __syncthreads();
#pragma unroll
    for (int rep = 0; rep < 4; ++rep) {
        int ii = rep * 256 + t;
        int d = ii >> 3, c = ii & 7;
        const u16* src = &Lt[d*66 + c*8];
        uint4 val;
        val.x = *(const unsigned int*)(src + 0);
        val.y = *(const unsigned int*)(src + 2);
        val.z = *(const unsigned int*)(src + 4);
        val.w = *(const unsigned int*)(src + 6);
        *(uint4*)(vt + ((size_t)(bg*DH + d))*T_SEQ + t0 + c*8) = val;
    }
}

// ---------------------------------------------------------------------------
// MFMA flash attention v10 (verified): v6 structure + in-register P.
// S^T = mfma(A=K, B=Q); K-rows staged permuted so chunk outputs concatenate
// in-register into the K=32 PV A-fragment. No P LDS traffic.
// ---------------------------------------------------------------------------
__global__ __launch_bounds__(256, 2)
void flash_attn_mfma(const u16* __restrict__ qh, const u16* __restrict__ kh,
                     const u16* __restrict__ vt, u16* __restrict__ y) {
    __shared__ __align__(16) u16 Ks[2][64*128];   // [buf][ldsrow][d] swizzled, rows permuted
    __shared__ __align__(16) u16 Vs[2][128*64];   // [buf][d][key]   swizzled

    const int t    = threadIdx.x;
    const int lane = t & 63, w = t >> 6;            // w = 0..3 = head-in-group
    const int l15  = lane & 15, quad = lane >> 4;
    const int bg   = blockIdx.y;
    const int b    = bg >> 2, g = bg & 3;
    const int chunk = b ? (int)blockIdx.x : (63 - (int)blockIdx.x);
    const int q0   = chunk * 32;
    const int h    = g * (NH / NG) + w;

    // tanh-poly coefficients pre-multiplied by log2(e)
    const float C0 =  1.4426950408889634f;
    const float C1 = -0.48089834696298777f;
    const float C2 =  0.19235933878519512f;
    const float C3 = -0.07785972536301652f;

    bf16x8 aq[2][4];
#pragma unroll
    for (int m = 0; m < 2; ++m) {
        const u16* qp = qh + ((size_t)(b*T_SEQ + q0 + m*16 + l15) * NH + h) * DH;
#pragma unroll
        for (int kc = 0; kc < 4; ++kc)
            aq[m][kc] = __builtin_bit_cast(bf16x8, *(const uint4*)(qp + kc*32 + quad*8));
    }

    f32x4 accO[2][8];
#pragma unroll
    for (int m = 0; m < 2; ++m)
#pragma unroll
        for (int nd = 0; nd < 8; ++nd) accO[m][nd] = (f32x4){0.f, 0.f, 0.f, 0.f};
    float ls[2] = {0.f, 0.f};

    const u16* kgb = kh + ((size_t)b*T_SEQ*NG + g)*DH;
    const u16* vgb = vt + ((size_t)(b*NG + g)*DH)*T_SEQ;

    const int krb = t >> 4, kcl = t & 15;
    const int vdb = t >> 3, vcl = t & 7;

    const int ktiles = q0/64 + 1;

#pragma unroll
    for (int j = 0; j < 4; ++j) {
        const int kr = j*16 + krb;
        const int rp = kr & 31;
        const int kphys = (kr & 32) + ((rp >> 2) & 3)*8 + (rp >> 4)*4 + (rp & 3);
        gll16(kgb + (size_t)kphys*(NG*DH) + ((kcl ^ (kr & 7)) << 3),
              (char*)Ks[0] + j*4096 + w*1024);
        const int vd = j*32 + vdb;
        gll16(vgb + (size_t)vd*T_SEQ + ((vcl ^ (vd & 7)) << 3),
              (char*)Vs[0] + j*4096 + w*1024);
    }

    for (int kt = 0; kt < ktiles; ++kt) {
        asm volatile("s_waitcnt vmcnt(0)" ::: "memory");
        __syncthreads();

        if (kt + 1 < ktiles) {
            const int k0n = (kt + 1) * 64, bn = (kt + 1) & 1;
#pragma unroll
            for (int j = 0; j < 4; ++j) {
                const int kr = j*16 + krb;
                const int rp = kr & 31;
                const int kphys = (kr & 32) + ((rp >> 2) & 3)*8 + (rp >> 4)*4 + (rp & 3);
                gll16(kgb + (size_t)(k0n + kphys)*(NG*DH) + ((kcl ^ (kr & 7)) << 3),
                      (char*)Ks[bn] + j*4096 + w*1024);
                const int vd = j*32 + vdb;
                gll16(vgb + (size_t)vd*T_SEQ + k0n + ((vcl ^ (vd & 7)) << 3),
                      (char*)Vs[bn] + j*4096 + w*1024);
            }
        }

        const u16* Kb = Ks[kt & 1];
        const u16* Vb = Vs[kt & 1];
        const int k0 = kt * 64;
        const bool diag = (kt == ktiles - 1);

        bf16x8 pa[2][2];
#pragma unroll
        for (int b32 = 0; b32 < 2; ++b32) {
            alignas(16) u16 pk0[8];
            alignas(16) u16 pk1[8];
#pragma unroll
            for (int sub = 0; sub < 2; ++sub) {
                const int kc16 = b32*2 + sub;
                const int krow = kc16*16 + l15;
                const int kswz = (krow & 7) << 3;
                f32x4 st0 = (f32x4){0.f,0.f,0.f,0.f};
                f32x4 st1 = (f32x4){0.f,0.f,0.f,0.f};
#pragma unroll
                for (int kc = 0; kc < 4; ++kc) {
                    bf16x8 ak = __builtin_bit_cast(bf16x8,
                        *(const uint4*)&Kb[krow*128 + ((kc*32 + quad*8) ^ kswz)]);
                    st0 = __builtin_amdgcn_mfma_f32_16x16x32_bf16(ak, aq[0][kc], st0, 0, 0, 0);
                    st1 = __builtin_amdgcn_mfma_f32_16x16x32_bf16(ak, aq[1][kc], st1, 0, 0, 0);
                }
#pragma unroll
                for (int m = 0; m < 2; ++m) {
                    const f32x4 st = m ? st1 : st0;
#pragma unroll
                    for (int r = 0; r < 4; ++r) {
                        float sv = st[r];
                        float z = sv * 0.02f;
                        float u = z * z;
                        float poly = fmaf(u, fmaf(u, fmaf(u, C3, C2), C1), C0);
                        float pv = __builtin_amdgcn_exp2f(sv * poly);
                        if (diag) {
                            const int keyg = k0 + b32*32 + quad*8 + sub*4 + r;
                            const int qg   = q0 + m*16 + l15;
                            pv = (keyg > qg) ? 0.f : pv;
                        }
                        ls[m] += pv;
                        if (m) pk1[sub*4 + r] = f2bf(pv);
                        else   pk0[sub*4 + r] = f2bf(pv);
                    }
                }
            }
            pa[0][b32] = __builtin_bit_cast(bf16x8, *(const uint4*)pk0);
            pa[1][b32] = __builtin_bit_cast(bf16x8, *(const uint4*)pk1);
        }

#pragma unroll
        for (int nd = 0; nd < 8; ++nd) {
            const int vrow = nd*16 + l15;
            const int vswz = (vrow & 7) << 3;
#pragma unroll
            for (int b32 = 0; b32 < 2; ++b32) {
                bf16x8 bv = __builtin_bit_cast(bf16x8,
                    *(const uint4*)&Vb[vrow*64 + ((b32*32 + quad*8) ^ vswz)]);
                accO[0][nd] = __builtin_amdgcn_mfma_f32_16x16x32_bf16(pa[0][b32], bv, accO[0][nd], 0, 0, 0);
                accO[1][nd] = __builtin_amdgcn_mfma_f32_16x16x32_bf16(pa[1][b32], bv, accO[1][nd], 0, 0, 0);
            }
        }
    }

#pragma unroll
    for (int m = 0; m < 2; ++m) {
        float v = ls[m];
        v += __shfl_xor(v, 16, 64);
        v += __shfl_xor(v, 32, 64);
        ls[m] = v;
    }

#pragma unroll
    for (int m = 0; m < 2; ++m)
#pragma unroll
        for (int r = 0; r < 4; ++r) {
            const float invl = 1.f / __shfl(ls[m], quad*4 + r, 64);
            u16* yp = y + (size_t)(b*T_SEQ + q0 + m*16 + quad*4 + r) * C_DIM + h*DH;
#pragma unroll
            for (int nd = 0; nd < 8; ++nd)
                yp[nd*16 + l15] = f2bf(accO[m][nd][r] * invl);
        }
}

// ---------------------------------------------------------------------------
extern "C" void kernel_launch(void* const* d_in, const int* in_sizes, int n_in,
                              void* d_out, int out_size, void* d_ws, size_t ws_size,
                              hipStream_t stream) {
    const float* x  = (const float*)d_in[0];
    const float* Wq = (const float*)d_in[1];
    const float* Wk = (const float*)d_in[2];
    const float* Wv = (const float*)d_in[3];
    const float* Wo = (const float*)d_in[4];
    const float* bo = (const float*)d_in[5];
    const float* qw = (const float*)d_in[6];
    const float* kw = (const float*)d_in[7];
    float* out = (float*)d_out;

    const size_t qE = (size_t)BATCH * T_SEQ * NH * DH;   // 8,388,608
    const size_t kE = (size_t)BATCH * T_SEQ * NG * DH;   // 2,097,152
    const size_t wqE = (size_t)C_DIM * C_DIM;            // 4,194,304
    const size_t wkE = (size_t)(NG*DH) * C_DIM;          // 1,048,576

    float* qf  = (float*)d_ws;          // qE floats (fp32 Q for rmsnorm)
    float* kf  = qf + qE;               // kE floats (fp32 K for rmsnorm)
    u16*   qh  = (u16*)(kf + kE);       // qE
    u16*   khb = qh + qE;               // kE
    u16*   vfh = khb + kE;              // kE  (B,T,G,D) bf16 from gemm_qkv
    u16*   vtb = vfh + kE;              // kE  (B,G,D,T) bf16
    u16*   xh  = vtb + kE;              // qE
    u16*   wqh = xh + qE;               // wqE
    u16*   wkh = wqh + wqE;             // wkE
    u16*   wvh = wkh + wkE;             // wkE
    u16*   woh = wvh + wkE;             // wqE
    float* cosT = (float*)(woh + wqE);  // 131072 floats
    float* sinT = cosT + 131072;        // 131072 floats
    u16*   yh  = (u16*)qf;              // qE (reuses qf: dead after norm)

    const int M = BATCH * T_SEQ;   // 4096
    dim3 blk(256);

    prep<<<dim3(9728), blk, 0, stream>>>(x, Wq, Wk, Wv, Wo,
                                         xh, wqh, wkh, wvh, woh, cosT, sinT);

    gemm_qkv<<<dim3(24, M/128), blk, 0, stream>>>(xh, wqh, wkh, wvh,
                                                  qf, kf, vfh);

    norm_qk_vt<<<dim3(M*NH/4 + M*NG/4 + 256), blk, 0, stream>>>(
        qf, kf, qw, kw, cosT, sinT, vfh, qh, khb, vtb);

    flash_attn_mfma<<<dim3(T_SEQ/32, BATCH*NG), blk, 0, stream>>>(qh, khb, vtb, yh);

    gemm_nt_bf16<<<dim3(C_DIM/128, M/128), blk, 0, stream>>>(yh, woh, bo, out, C_DIM, C_DIM);
}

// Round 10
// 317.776 us; speedup vs baseline: 1.1047x; 1.1047x over previous
//
#include <hip/hip_runtime.h>
#include <math.h>

#define T_SEQ 2048
#define C_DIM 2048
#define NH    16
#define NG    4
#define DH    128
#define BATCH 2

typedef unsigned short u16;
typedef __bf16 bf16_t;
typedef bf16_t bf16x8 __attribute__((ext_vector_type(8)));
typedef float  f32x4  __attribute__((ext_vector_type(4)));

static __device__ __forceinline__ u16 f2bf(float f) {
    return __builtin_bit_cast(u16, (__bf16)f);
}
static __device__ __forceinline__ float bf2f(u16 u) {
    return (float)__builtin_bit_cast(__bf16, u);
}

// async global->LDS, 16B per lane. lds must be wave-uniform base; HW adds lane*16.
static __device__ __forceinline__ void gll16(const void* g, void* lds) {
    __builtin_amdgcn_global_load_lds(
        (const __attribute__((address_space(1))) void*)(unsigned long long)(g),
        (__attribute__((address_space(3))) void*)(unsigned int)(unsigned long long)(lds),
        16, 0, 0);
}

// ---------------------------------------------------------------------------
// fused fp32->bf16 cast for x, Wq, Wk, Wv (8 elems/thread, flat if-chain)
// chunk counts: x 1048576 | Wq 524288 | Wk 131072 | Wv 131072  (sum = 7168*256)
// ---------------------------------------------------------------------------
__global__ __launch_bounds__(256)
void cast_multi(const float* __restrict__ x,  const float* __restrict__ wq,
                const float* __restrict__ wk, const float* __restrict__ wv,
                u16* __restrict__ xo, u16* __restrict__ wqo,
                u16* __restrict__ wko, u16* __restrict__ wvo) {
    int i = blockIdx.x * 256 + threadIdx.x;
    const float* src; u16* dst; int off;
    if (i < 1048576)      { src = x;  dst = xo;  off = i; }
    else if (i < 1572864) { src = wq; dst = wqo; off = i - 1048576; }
    else if (i < 1703936) { src = wk; dst = wko; off = i - 1572864; }
    else                  { src = wv; dst = wvo; off = i - 1703936; }
    const float4* p = (const float4*)src + (size_t)off * 2;
    float4 a = p[0], b = p[1];
    u16 u[8] = {f2bf(a.x), f2bf(a.y), f2bf(a.z), f2bf(a.w),
                f2bf(b.x), f2bf(b.y), f2bf(b.z), f2bf(b.w)};
    *(uint4*)(dst + (size_t)off * 8) = *(const uint4*)u;
}

__global__ __launch_bounds__(256)
void cast_f32_bf16(const float* __restrict__ in, u16* __restrict__ out, int n8) {
    int i = blockIdx.x * 256 + threadIdx.x;
    if (i >= n8) return;
    const float4* p = (const float4*)in + (size_t)i * 2;
    float4 a = p[0], b = p[1];
    u16 u[8] = {f2bf(a.x), f2bf(a.y), f2bf(a.z), f2bf(a.w),
                f2bf(b.x), f2bf(b.y), f2bf(b.z), f2bf(b.w)};
    *(uint4*)(out + (size_t)i * 8) = *(const uint4*)u;
}

// ---------------------------------------------------------------------------
// rotary tables: cos/sin(t * 10000^(-l/64)) for t in [0,2048), l in [0,64).
// ---------------------------------------------------------------------------
__global__ __launch_bounds__(256)
void rope_tables(float* __restrict__ cosT, float* __restrict__ sinT) {
    int i = blockIdx.x * 256 + threadIdx.x;     // 131072 entries
    int tp = i >> 6, ln = i & 63;
    float invfreq = __builtin_amdgcn_exp2f(-(float)ln * (13.287712379549449f / 64.0f));
    float s, c;
    sincosf((float)tp * invfreq, &s, &c);
    cosT[i] = c;
    sinT[i] = s;
}

// ---------------------------------------------------------------------------
// GEMM core: acc(64x64 per wave) = A_bf16(M,K) @ B_bf16(N,K)^T for one
// 128x128 tile, BK=32, 4 waves. Epilogue supplied by caller.
// ---------------------------------------------------------------------------
static __device__ __forceinline__ void gemm_core(
        u16* As, u16* Bs,
        const u16* __restrict__ A, const u16* __restrict__ B,
        int K, int m0, int n0, f32x4 (&acc)[4][4]) {
    const int t    = threadIdx.x;
    const int lane = t & 63, w = t >> 6;
    const int l15  = lane & 15, quad = lane >> 4;
    const int wr   = w >> 1, wc = w & 1;

#pragma unroll
    for (int mt = 0; mt < 4; ++mt)
#pragma unroll
        for (int nt = 0; nt < 4; ++nt) acc[mt][nt] = (f32x4){0.f, 0.f, 0.f, 0.f};

    const int off0 = w*2048 + lane*16;
    const int r0 = off0 >> 6,          c0 = (off0 & 63) >> 1;
    const int r1 = (off0+1024) >> 6,   c1 = ((off0+1024) & 63) >> 1;
    const u16* Ag0 = A + (size_t)(m0 + r0) * K + c0;
    const u16* Ag1 = A + (size_t)(m0 + r1) * K + c1;
    const u16* Bg0 = B + (size_t)(n0 + r0) * K + c0;
    const u16* Bg1 = B + (size_t)(n0 + r1) * K + c1;
    char* AsB = (char*)As; char* BsB = (char*)Bs;
    const int ldsOff0 = w*2048, ldsOff1 = w*2048 + 1024;

    for (int k0 = 0; k0 < K; k0 += 32) {
        gll16(Ag0 + k0, AsB + ldsOff0);
        gll16(Ag1 + k0, AsB + ldsOff1);
        gll16(Bg0 + k0, BsB + ldsOff0);
        gll16(Bg1 + k0, BsB + ldsOff1);
        __syncthreads();
        bf16x8 af[4], bf[4];
#pragma unroll
        for (int mt = 0; mt < 4; ++mt)
            af[mt] = __builtin_bit_cast(bf16x8,
                *(const uint4*)&As[(wr*64 + mt*16 + l15)*32 + quad*8]);
#pragma unroll
        for (int nt = 0; nt < 4; ++nt)
            bf[nt] = __builtin_bit_cast(bf16x8,
                *(const uint4*)&Bs[(wc*64 + nt*16 + l15)*32 + quad*8]);
#pragma unroll
        for (int mt = 0; mt < 4; ++mt)
#pragma unroll
            for (int nt = 0; nt < 4; ++nt)
                acc[mt][nt] = __builtin_amdgcn_mfma_f32_16x16x32_bf16(
                                  af[mt], bf[nt], acc[mt][nt], 0, 0, 0);
        __syncthreads();
    }
}

__global__ __launch_bounds__(256)
void gemm_nt_bf16(const u16* __restrict__ A, const u16* __restrict__ B,
                  const float* __restrict__ bias, float* __restrict__ C,
                  int N, int K) {
    __shared__ __align__(16) u16 As[128*32];
    __shared__ __align__(16) u16 Bs[128*32];
    const int m0 = blockIdx.y*128, n0 = blockIdx.x*128;
    f32x4 acc[4][4];
    gemm_core(As, Bs, A, B, K, m0, n0, acc);

    const int t    = threadIdx.x;
    const int lane = t & 63, w = t >> 6;
    const int l15  = lane & 15, quad = lane >> 4;
    const int wr   = w >> 1, wc = w & 1;
#pragma unroll
    for (int mt = 0; mt < 4; ++mt)
#pragma unroll
        for (int nt = 0; nt < 4; ++nt) {
            const int col = n0 + wc*64 + nt*16 + l15;
            const float bv = bias ? bias[col] : 0.f;
#pragma unroll
            for (int r = 0; r < 4; ++r) {
                const int row = m0 + wr*64 + mt*16 + quad*4 + r;
                C[(size_t)row * N + col] = acc[mt][nt][r] + bv;
            }
        }
}

// ---------------------------------------------------------------------------
// Fused Q/K/V projections (v14). blockIdx.x 0..15 -> Q, 16..19 -> K, 20..23 -> V.
// UNIFORM branchless epilogue (r8/r9 post-mortem: dual-dtype epilogue paths
// pushed VGPR 76->92, MfmaUtil 30->20, +32us): all three outputs bf16 via the
// single round-6 store loop + f2bf. Halves Q/K intermediate traffic.
// ---------------------------------------------------------------------------
__global__ __launch_bounds__(256)
void gemm_qkv(const u16* __restrict__ A,  const u16* __restrict__ Bq,
              const u16* __restrict__ Bk, const u16* __restrict__ Bv,
              u16* __restrict__ Cq, u16* __restrict__ Ck, u16* __restrict__ Cv) {
    __shared__ __align__(16) u16 As[128*32];
    __shared__ __align__(16) u16 Bs[128*32];
    const int bx = blockIdx.x;
    const u16* B; u16* C; int N, n0;
    if (bx < 16)      { B = Bq; C = Cq; N = 2048; n0 = bx * 128; }
    else if (bx < 20) { B = Bk; C = Ck; N = 512;  n0 = (bx-16) * 128; }
    else              { B = Bv; C = Cv; N = 512;  n0 = (bx-20) * 128; }
    const int m0 = blockIdx.y * 128;

    f32x4 acc[4][4];
    gemm_core(As, Bs, A, B, 2048, m0, n0, acc);

    const int t    = threadIdx.x;
    const int lane = t & 63, w = t >> 6;
    const int l15  = lane & 15, quad = lane >> 4;
    const int wr   = w >> 1, wc = w & 1;
#pragma unroll
    for (int mt = 0; mt < 4; ++mt)
#pragma unroll
        for (int nt = 0; nt < 4; ++nt) {
            const int col = n0 + wc*64 + nt*16 + l15;
#pragma unroll
            for (int r = 0; r < 4; ++r) {
                const int row = m0 + wr*64 + mt*16 + quad*4 + r;
                C[(size_t)row * N + col] = f2bf(acc[mt][nt][r]);
            }
        }
}

// ---------------------------------------------------------------------------
// Fused RMSNorm + RoPE for q and k, bf16 in -> bf16 out (norm math in fp32).
// blocks [0, 16384): q rows; [16384, 20480): k rows. One wave per D=128 row.
// cos/sin from precomputed tables (L2-resident).
// ---------------------------------------------------------------------------
__global__ __launch_bounds__(256)
void rmsnorm_rope_qk(const u16* __restrict__ qraw, const u16* __restrict__ kraw,
                     const float* __restrict__ qw, const float* __restrict__ kw,
                     const float* __restrict__ cosT, const float* __restrict__ sinT,
                     u16* __restrict__ qo, u16* __restrict__ ko) {
    const int blk  = blockIdx.x;
    const int sub  = threadIdx.x >> 6;
    const int lane = threadIdx.x & 63;
    const u16* in; const float* w; u16* out; int row, nheads; float scale;
    if (blk < 16384) {
        in = qraw; w = qw; out = qo; nheads = NH; scale = 0.08838834764831845f;
        row = blk * 4 + sub;
    } else {
        in = kraw; w = kw; out = ko; nheads = NG; scale = 1.0f;
        row = (blk - 16384) * 4 + sub;
    }
    const u16* p = in + (size_t)row * 128;
    float x1 = bf2f(p[lane]), x2 = bf2f(p[lane + 64]);
    float ss = x1*x1 + x2*x2;
#pragma unroll
    for (int off = 32; off >= 1; off >>= 1) ss += __shfl_xor(ss, off, 64);
    float inv = 1.0f / (sqrtf(ss * (1.0f/128.0f)) + 1e-6f);
    float x1n = w[lane]      * x1 * inv;
    float x2n = w[lane + 64] * x2 * inv;
    int tpos = (row / nheads) & (T_SEQ - 1);
    float c = cosT[tpos*64 + lane];
    float s = sinT[tpos*64 + lane];
    out[(size_t)row*128 + lane]      = f2bf((x1n * c + x2n * s) * scale);
    out[(size_t)row*128 + lane + 64] = f2bf((x2n * c - x1n * s) * scale);
}

// ---------------------------------------------------------------------------
// V transpose (bf16 in, r8-verified): vfh (B,T,G,D) -> vt (B,G,D,T).
// ---------------------------------------------------------------------------
__global__ __launch_bounds__(256)
void v_cast_transpose(const u16* __restrict__ v, u16* __restrict__ vt) {
    __shared__ u16 Lt[128 * 66];
    const int t  = threadIdx.x;
    const int t0 = blockIdx.x * 64;
    const int bg = blockIdx.y;
    const int b  = bg / NG, g = bg % NG;
#pragma unroll
    for (int rep = 0; rep < 4; ++rep) {
        int idx = rep * 256 + t;               // 0..1023
        int i   = idx >> 4;                    // row 0..63
        int c   = idx & 15;                    // 8-elem chunk
        uint4 vv = *(const uint4*)(v + ((size_t)(b*T_SEQ + t0 + i)*NG + g)*DH + c*8);
        const u16* pv = (const u16*)&vv;
#pragma unroll
        for (int jj = 0; jj < 8; ++jj)
            Lt[(c*8 + jj)*66 + i] = pv[jj];
    }
    __syncthreads();
#pragma unroll
    for (int rep = 0; rep < 4; ++rep) {
        int idx = rep * 256 + t;
        int d = idx >> 3, c = idx & 7;
        const u16* src = &Lt[d*66 + c*8];
        uint4 val;
        val.x = *(const unsigned int*)(src + 0);
        val.y = *(const unsigned int*)(src + 2);
        val.z = *(const unsigned int*)(src + 4);
        val.w = *(const unsigned int*)(src + 6);
        *(uint4*)(vt + ((size_t)(bg*DH + d))*T_SEQ + t0 + c*8) = val;
    }
}

// ---------------------------------------------------------------------------
// MFMA flash attention v10 (verified): v6 structure + in-register P.
// S^T = mfma(A=K, B=Q); K-rows staged permuted so chunk outputs concatenate
// in-register into the K=32 PV A-fragment. No P LDS traffic.
// ---------------------------------------------------------------------------
__global__ __launch_bounds__(256, 2)
void flash_attn_mfma(const u16* __restrict__ qh, const u16* __restrict__ kh,
                     const u16* __restrict__ vt, u16* __restrict__ y) {
    __shared__ __align__(16) u16 Ks[2][64*128];   // [buf][ldsrow][d] swizzled, rows permuted
    __shared__ __align__(16) u16 Vs[2][128*64];   // [buf][d][key]   swizzled

    const int t    = threadIdx.x;
    const int lane = t & 63, w = t >> 6;            // w = 0..3 = head-in-group
    const int l15  = lane & 15, quad = lane >> 4;
    const int bg   = blockIdx.y;
    const int b    = bg >> 2, g = bg & 3;
    const int chunk = b ? (int)blockIdx.x : (63 - (int)blockIdx.x);
    const int q0   = chunk * 32;
    const int h    = g * (NH / NG) + w;

    // tanh-poly coefficients pre-multiplied by log2(e)
    const float C0 =  1.4426950408889634f;
    const float C1 = -0.48089834696298777f;
    const float C2 =  0.19235933878519512f;
    const float C3 = -0.07785972536301652f;

    bf16x8 aq[2][4];
#pragma unroll
    for (int m = 0; m < 2; ++m) {
        const u16* qp = qh + ((size_t)(b*T_SEQ + q0 + m*16 + l15) * NH + h) * DH;
#pragma unroll
        for (int kc = 0; kc < 4; ++kc)
            aq[m][kc] = __builtin_bit_cast(bf16x8, *(const uint4*)(qp + kc*32 + quad*8));
    }

    f32x4 accO[2][8];
#pragma unroll
    for (int m = 0; m < 2; ++m)
#pragma unroll
        for (int nd = 0; nd < 8; ++nd) accO[m][nd] = (f32x4){0.f, 0.f, 0.f, 0.f};
    float ls[2] = {0.f, 0.f};

    const u16* kgb = kh + ((size_t)b*T_SEQ*NG + g)*DH;
    const u16* vgb = vt + ((size_t)(b*NG + g)*DH)*T_SEQ;

    const int krb = t >> 4, kcl = t & 15;
    const int vdb = t >> 3, vcl = t & 7;

    const int ktiles = q0/64 + 1;

#pragma unroll
    for (int j = 0; j < 4; ++j) {
        const int kr = j*16 + krb;
        const int rp = kr & 31;
        const int kphys = (kr & 32) + ((rp >> 2) & 3)*8 + (rp >> 4)*4 + (rp & 3);
        gll16(kgb + (size_t)kphys*(NG*DH) + ((kcl ^ (kr & 7)) << 3),
              (char*)Ks[0] + j*4096 + w*1024);
        const int vd = j*32 + vdb;
        gll16(vgb + (size_t)vd*T_SEQ + ((vcl ^ (vd & 7)) << 3),
              (char*)Vs[0] + j*4096 + w*1024);
    }

    for (int kt = 0; kt < ktiles; ++kt) {
        asm volatile("s_waitcnt vmcnt(0)" ::: "memory");
        __syncthreads();

        if (kt + 1 < ktiles) {
            const int k0n = (kt + 1) * 64, bn = (kt + 1) & 1;
#pragma unroll
            for (int j = 0; j < 4; ++j) {
                const int kr = j*16 + krb;
                const int rp = kr & 31;
                const int kphys = (kr & 32) + ((rp >> 2) & 3)*8 + (rp >> 4)*4 + (rp & 3);
                gll16(kgb + (size_t)(k0n + kphys)*(NG*DH) + ((kcl ^ (kr & 7)) << 3),
                      (char*)Ks[bn] + j*4096 + w*1024);
                const int vd = j*32 + vdb;
                gll16(vgb + (size_t)vd*T_SEQ + k0n + ((vcl ^ (vd & 7)) << 3),
                      (char*)Vs[bn] + j*4096 + w*1024);
            }
        }

        const u16* Kb = Ks[kt & 1];
        const u16* Vb = Vs[kt & 1];
        const int k0 = kt * 64;
        const bool diag = (kt == ktiles - 1);

        bf16x8 pa[2][2];
#pragma unroll
        for (int b32 = 0; b32 < 2; ++b32) {
            alignas(16) u16 pk0[8];
            alignas(16) u16 pk1[8];
#pragma unroll
            for (int sub = 0; sub < 2; ++sub) {
                const int kc16 = b32*2 + sub;
                const int krow = kc16*16 + l15;
                const int kswz = (krow & 7) << 3;
                f32x4 st0 = (f32x4){0.f,0.f,0.f,0.f};
                f32x4 st1 = (f32x4){0.f,0.f,0.f,0.f};
#pragma unroll
                for (int kc = 0; kc < 4; ++kc) {
                    bf16x8 ak = __builtin_bit_cast(bf16x8,
                        *(const uint4*)&Kb[krow*128 + ((kc*32 + quad*8) ^ kswz)]);
                    st0 = __builtin_amdgcn_mfma_f32_16x16x32_bf16(ak, aq[0][kc], st0, 0, 0, 0);
                    st1 = __builtin_amdgcn_mfma_f32_16x16x32_bf16(ak, aq[1][kc], st1, 0, 0, 0);
                }
#pragma unroll
                for (int m = 0; m < 2; ++m) {
                    const f32x4 st = m ? st1 : st0;
#pragma unroll
                    for (int r = 0; r < 4; ++r) {
                        float sv = st[r];
                        float z = sv * 0.02f;
                        float u = z * z;
                        float poly = fmaf(u, fmaf(u, fmaf(u, C3, C2), C1), C0);
                        float pv = __builtin_amdgcn_exp2f(sv * poly);
                        if (diag) {
                            const int keyg = k0 + b32*32 + quad*8 + sub*4 + r;
                            const int qg   = q0 + m*16 + l15;
                            pv = (keyg > qg) ? 0.f : pv;
                        }
                        ls[m] += pv;
                        if (m) pk1[sub*4 + r] = f2bf(pv);
                        else   pk0[sub*4 + r] = f2bf(pv);
                    }
                }
            }
            pa[0][b32] = __builtin_bit_cast(bf16x8, *(const uint4*)pk0);
            pa[1][b32] = __builtin_bit_cast(bf16x8, *(const uint4*)pk1);
        }

#pragma unroll
        for (int nd = 0; nd < 8; ++nd) {
            const int vrow = nd*16 + l15;
            const int vswz = (vrow & 7) << 3;
#pragma unroll
            for (int b32 = 0; b32 < 2; ++b32) {
                bf16x8 bv = __builtin_bit_cast(bf16x8,
                    *(const uint4*)&Vb[vrow*64 + ((b32*32 + quad*8) ^ vswz)]);
                accO[0][nd] = __builtin_amdgcn_mfma_f32_16x16x32_bf16(pa[0][b32], bv, accO[0][nd], 0, 0, 0);
                accO[1][nd] = __builtin_amdgcn_mfma_f32_16x16x32_bf16(pa[1][b32], bv, accO[1][nd], 0, 0, 0);
            }
        }
    }

#pragma unroll
    for (int m = 0; m < 2; ++m) {
        float v = ls[m];
        v += __shfl_xor(v, 16, 64);
        v += __shfl_xor(v, 32, 64);
        ls[m] = v;
    }

#pragma unroll
    for (int m = 0; m < 2; ++m)
#pragma unroll
        for (int r = 0; r < 4; ++r) {
            const float invl = 1.f / __shfl(ls[m], quad*4 + r, 64);
            u16* yp = y + (size_t)(b*T_SEQ + q0 + m*16 + quad*4 + r) * C_DIM + h*DH;
#pragma unroll
            for (int nd = 0; nd < 8; ++nd)
                yp[nd*16 + l15] = f2bf(accO[m][nd][r] * invl);
        }
}

// ---------------------------------------------------------------------------
extern "C" void kernel_launch(void* const* d_in, const int* in_sizes, int n_in,
                              void* d_out, int out_size, void* d_ws, size_t ws_size,
                              hipStream_t stream) {
    const float* x  = (const float*)d_in[0];
    const float* Wq = (const float*)d_in[1];
    const float* Wk = (const float*)d_in[2];
    const float* Wv = (const float*)d_in[3];
    const float* Wo = (const float*)d_in[4];
    const float* bo = (const float*)d_in[5];
    const float* qw = (const float*)d_in[6];
    const float* kw = (const float*)d_in[7];
    float* out = (float*)d_out;

    const size_t qE = (size_t)BATCH * T_SEQ * NH * DH;   // 8,388,608
    const size_t kE = (size_t)BATCH * T_SEQ * NG * DH;   // 2,097,152
    const size_t wqE = (size_t)C_DIM * C_DIM;            // 4,194,304
    const size_t wkE = (size_t)(NG*DH) * C_DIM;          // 1,048,576

    u16*   qraw = (u16*)d_ws;           // qE  bf16 Q pre-norm
    u16*   kraw = qraw + qE;            // kE  bf16 K pre-norm
    u16*   vfh  = kraw + kE;            // kE  bf16 V (B,T,G,D)
    u16*   qh   = vfh + kE;             // qE
    u16*   khb  = qh + qE;              // kE
    u16*   vtb  = khb + kE;             // kE  (B,G,D,T)
    u16*   xh   = vtb + kE;             // qE
    u16*   wqh  = xh + qE;              // wqE
    u16*   wkh  = wqh + wqE;            // wkE
    u16*   wvh  = wkh + wkE;            // wkE
    u16*   woh  = wvh + wkE;            // wqE
    float* cosT = (float*)(woh + wqE);  // 131072 floats
    float* sinT = cosT + 131072;        // 131072 floats
    u16*   yh   = qraw;                 // reuse (dead after rmsnorm)

    const int M = BATCH * T_SEQ;   // 4096
    dim3 blk(256);

    rope_tables<<<dim3(512), blk, 0, stream>>>(cosT, sinT);

    cast_multi<<<dim3(7168), blk, 0, stream>>>(x, Wq, Wk, Wv, xh, wqh, wkh, wvh);

    gemm_qkv<<<dim3(24, M/128), blk, 0, stream>>>(xh, wqh, wkh, wvh,
                                                  qraw, kraw, vfh);

    rmsnorm_rope_qk<<<dim3(M*NH/4 + M*NG/4), blk, 0, stream>>>(
        qraw, kraw, qw, kw, cosT, sinT, qh, khb);
    v_cast_transpose<<<dim3(T_SEQ/64, BATCH*NG), blk, 0, stream>>>(vfh, vtb);

    cast_f32_bf16<<<dim3(wqE/8/256), blk, 0, stream>>>(Wo, woh, wqE/8);

    flash_attn_mfma<<<dim3(T_SEQ/32, BATCH*NG), blk, 0, stream>>>(qh, khb, vtb, yh);

    gemm_nt_bf16<<<dim3(C_DIM/128, M/128), blk, 0, stream>>>(yh, woh, bo, out, C_DIM, C_DIM);
}